// Round 12
// baseline (326.861 us; speedup 1.0000x reference)
//
#include <hip/hip_runtime.h>

#define TT 128
#define BB 32
#define NN (TT*BB)   // 4096

typedef float f4 __attribute__((ext_vector_type(4)));
typedef float f32x4 __attribute__((ext_vector_type(4)));
typedef short s8 __attribute__((ext_vector_type(8)));
typedef short bf16x8 __attribute__((ext_vector_type(8)));
typedef short s4v __attribute__((ext_vector_type(4)));

__device__ __forceinline__ float bf2f(unsigned short u){
  union{unsigned int i; float f;} x; x.i = ((unsigned int)u)<<16; return x.f;
}
__device__ __forceinline__ unsigned short f2bf(float f){
  union{float ff; unsigned int i;} x; x.ff=f;
  unsigned int r = x.i + 0x7FFFu + ((x.i>>16)&1u);
  return (unsigned short)(r>>16);
}
__device__ __forceinline__ float fsig(float x){
  return __builtin_amdgcn_rcpf(1.f + __expf(-x));
}
__device__ __forceinline__ float ftanh(float x){
  return 1.f - 2.f*__builtin_amdgcn_rcpf(1.f + __expf(2.f*x));
}
__device__ __forceinline__ void gload_lds16(const void* g, void* lds){
  __builtin_amdgcn_global_load_lds(
    (const __attribute__((address_space(1))) unsigned int*)g,
    (__attribute__((address_space(3))) unsigned int*)lds, 16, 0, 0);
}
// load 8 f32 from global, convert to bf16x8 in-register
__device__ __forceinline__ bf16x8 ldcvt8(const float* p){
  f4 u0 = *(const f4*)p;
  f4 u1 = *(const f4*)(p + 4);
  bf16x8 r;
  #pragma unroll
  for(int j=0;j<4;j++){ r[j] = (short)f2bf(u0[j]); r[4+j] = (short)f2bf(u1[j]); }
  return r;
}

// ================= merged weight prep (1 launch) ===========================
__global__ __launch_bounds__(256) void prep_all(
    const float* __restrict__ W1, const float* __restrict__ W2,
    const float* __restrict__ W3, const float* __restrict__ Wfc,
    const float* __restrict__ W_ih, const float* __restrict__ W_hh,
    unsigned short* __restrict__ w1c, unsigned short* __restrict__ w2c,
    unsigned short* __restrict__ w3c, unsigned short* __restrict__ wfcc,
    unsigned short* __restrict__ wihc, unsigned short* __restrict__ whhc){
  int i = blockIdx.x*256 + threadIdx.x;
  if(i < 1605632){
    int nn = i/3136; int rem = i - nn*3136; int sp = rem >> 6; int ci = rem & 63;
    wfcc[i] = f2bf(Wfc[nn*3136 + ci*49 + sp]); return;
  }
  i -= 1605632;
  if(i < 262144){ wihc[i] = f2bf(W_ih[i]); return; }
  i -= 262144;
  if(i < 65536){ whhc[i] = f2bf(W_hh[i]); return; }
  i -= 65536;
  if(i < 36864){
    int co = i/576; int rem = i - co*576; int khw = rem >> 6; int ci = rem & 63;
    w3c[i] = f2bf(W3[(co*64 + ci)*9 + khw]); return;
  }
  i -= 36864;
  if(i < 32768){
    int co = i >> 9; int rem = i & 511; int khw = rem >> 5; int ci = rem & 31;
    w2c[i] = f2bf(W2[(co*32 + ci)*16 + khw]); return;
  }
  i -= 32768;
  if(i < 2048){ w1c[i] = f2bf(W1[i] * (1.f/255.f)); }
}

// ================= fused conv1+conv2, no-staging variant ===================
// 4096 blocks x 512 thr (8 waves). LDS = z1s ONLY (25.6 KB).
// conv1: x B-frags read DIRECTLY from global (f4 pairs + in-reg cvt), w1
//   frags from global; D[ch][pixel] -> z1s swizzled b64 writes.
// conv2: identical to R11 (wave = (cg, mj), one w2 stream, 2-deep prefetch).
__global__ __launch_bounds__(512) void conv12_k(
    const float* __restrict__ x,
    const unsigned short* __restrict__ w1c, const float* __restrict__ b1,
    const unsigned short* __restrict__ w2c, const float* __restrict__ b2,
    unsigned short* __restrict__ z2){
  __shared__ unsigned short z1s[200*64];    // 25600 B (swizzled)
  int t = threadIdx.x;
  int n = blockIdx.x;
  int w = t >> 6, l = t & 63;
  int lr = l & 15, lg = l >> 4;

  // ---- conv1: D[ch][pixel] = mfma(w1_frag, x_frag), tiles strided by 8 ----
  {
    bf16x8 wf1[2][2];   // [nt][s] from global (L2-broadcast)
    #pragma unroll
    for(int nt=0;nt<2;nt++)
      #pragma unroll
      for(int s=0;s<2;s++)
        wf1[nt][s] = *(const bf16x8*)&w1c[(nt*16+lr)*64 + s*32 + lg*8];
    f4 b1v[2];
    b1v[0] = *(const f4*)&b1[lg*4];
    b1v[1] = *(const f4*)&b1[16 + lg*4];
    const float* xb = x + (size_t)n*7056;
    for(int mt=w; mt<25; mt+=8){
      int p = mt*16 + lr;
      int oh = p/20, ow = p - oh*20;
      const float* xr = xb + (size_t)(oh*4 + lg)*84 + ow*4;
      bf16x8 a0 = ldcvt8(xr);           // rows oh*4+lg,   k = lg*8 + kw
      bf16x8 a1 = ldcvt8(xr + 4*84);    // rows oh*4+4+lg, k = 32 + lg*8 + kw
      f32x4 acc[2] = {};
      acc[0] = __builtin_amdgcn_mfma_f32_16x16x32_bf16(wf1[0][0], a0, acc[0], 0,0,0);
      acc[0] = __builtin_amdgcn_mfma_f32_16x16x32_bf16(wf1[0][1], a1, acc[0], 0,0,0);
      acc[1] = __builtin_amdgcn_mfma_f32_16x16x32_bf16(wf1[1][0], a0, acc[1], 0,0,0);
      acc[1] = __builtin_amdgcn_mfma_f32_16x16x32_bf16(wf1[1][1], a1, acc[1], 0,0,0);
      int row = p >> 1, par = (p & 1) << 6, swz = (row & 7) << 4;
      #pragma unroll
      for(int nt=0;nt<2;nt++){
        s4v hp;
        #pragma unroll
        for(int reg=0;reg<4;reg++){
          float v = acc[nt][reg] + b1v[nt][reg];
          v = v>0.f ? v : 0.f;
          hp[reg] = (short)f2bf(v);
        }
        int bo = (par + (nt*16 + lg*4)*2) ^ swz;
        *(s4v*)((char*)z1s + row*128 + bo) = hp;
      }
    }
  }
  __syncthreads();

  // ---- conv2: wave (cg = w>>1 in 0..3, mj = w&1) ----
  {
    int cg = w >> 1, mj = w & 1;
    int rb2[3];
    #pragma unroll
    for(int m=0;m<3;m++){
      int q = (3*mj+m)*16 + lr; if(q > 80) q = 80;
      int oh = q/9, ow = q - oh*9;
      rb2[m] = 2*oh*20 + 2*ow;
    }
    const unsigned short* wrow = w2c + (size_t)(cg*16+lr)*512 + lg*8;
    bf16x8 bq0 = *(const bf16x8*)(wrow);
    bf16x8 bq1 = *(const bf16x8*)(wrow + 32);
    f32x4 acc2[3] = {};
    #pragma unroll
    for(int s=0;s<16;s++){
      bf16x8 acur = (s & 1) ? bq1 : bq0;
      if(s+2 < 16){
        bf16x8 bn = *(const bf16x8*)(wrow + (s+2)*32);
        if(s & 1) bq1 = bn; else bq0 = bn;
      }
      int kh = s>>2, kw = s&3;
      #pragma unroll
      for(int m=0;m<3;m++){
        int p = rb2[m] + kh*20 + kw;
        int row = p >> 1;
        int bo = (((p&1)<<6) + (lg<<4)) ^ ((row&7)<<4);
        bf16x8 bf = *(const bf16x8*)((const char*)z1s + row*128 + bo);
        acc2[m] = __builtin_amdgcn_mfma_f32_16x16x32_bf16(acur, bf, acc2[m], 0,0,0);
      }
    }
    f4 b2v = *(const f4*)&b2[cg*16 + lg*4];
    #pragma unroll
    for(int m=0;m<3;m++){
      int q = (3*mj+m)*16 + lr;
      if(q < 81){
        s4v hp;
        #pragma unroll
        for(int reg=0;reg<4;reg++){
          float v = acc2[m][reg] + b2v[reg];
          v = v>0.f ? v : 0.f;
          hp[reg] = (short)f2bf(v);
        }
        *(s4v*)&z2[((size_t)n*81 + q)*64 + cg*16 + lg*4] = hp;
      }
    }
  }
}

// ================= unified MFMA GEMM =======================================
// MODE 0: plain A rows. MODE 2: conv3 implicit (z2 NHWC 9x9x64).
// SWZ: XCD-chunked bm remap (needs gridDim.y % 8 == 0).
template<int MODE, int OUTBF16, int RELU, int SWZ>
__global__ __launch_bounds__(256) void mgemm_k(
    const unsigned short* __restrict__ A, const unsigned short* __restrict__ B,
    const float* __restrict__ bias1, const float* __restrict__ bias2,
    void* __restrict__ Cout, int K, int Nld, int nout){
  __shared__ unsigned short As[128*40];
  __shared__ unsigned short Bs[64*40];
  int t = threadIdx.x;
  int bm = blockIdx.y, bn = blockIdx.x;
  if(SWZ){
    int cpx = gridDim.y >> 3;
    bm = (bm & 7)*cpx + (bm >> 3);
  }
  int arow = t >> 1, ahalf = t & 1;
  int gm = bm*128 + arow;
  const unsigned short* abase;
  if(MODE == 0){
    abase = A + (size_t)gm*K + ahalf*16;
  } else {
    int n = gm/49; int r = gm - n*49; int oh = r/7; int ow = r - oh*7;
    abase = A + (((size_t)n*9 + oh)*9 + ow)*64 + ahalf*16;
  }
  int brow = t >> 2, bq = t & 3;
  const unsigned short* bbase = B + (size_t)(bn*64 + brow)*K + bq*8;
  int l = t & 63, w = t >> 6;
  int wr = w >> 1, wc = w & 1;
  int lr = l & 15, lk = (l >> 4)*8;
  f32x4 acc[4][2] = {};
  int nsteps = K >> 5;
  for(int s=0; s<nsteps; s++){
    const unsigned short* src;
    if(MODE == 0){
      src = abase + s*32;
    } else {
      int khw = s >> 1; int kh = khw/3; int kw = khw - kh*3;
      src = abase + (kh*9 + kw)*64 + (s & 1)*32;
    }
    bf16x8 a0 = *(const bf16x8*)src;
    bf16x8 a1 = *(const bf16x8*)(src + 8);
    *(bf16x8*)&As[arow*40 + ahalf*16] = a0;
    *(bf16x8*)&As[arow*40 + ahalf*16 + 8] = a1;
    bf16x8 bv = *(const bf16x8*)(bbase + s*32);
    *(bf16x8*)&Bs[brow*40 + bq*8] = bv;
    __syncthreads();
    bf16x8 af[4];
    #pragma unroll
    for(int mf=0; mf<4; mf++)
      af[mf] = *(const bf16x8*)&As[(wr*64 + mf*16 + lr)*40 + lk];
    bf16x8 b0 = *(const bf16x8*)&Bs[(wc*32 + lr)*40 + lk];
    bf16x8 b1 = *(const bf16x8*)&Bs[(wc*32 + 16 + lr)*40 + lk];
    #pragma unroll
    for(int mf=0; mf<4; mf++){
      acc[mf][0] = __builtin_amdgcn_mfma_f32_16x16x32_bf16(af[mf], b0, acc[mf][0], 0, 0, 0);
      acc[mf][1] = __builtin_amdgcn_mfma_f32_16x16x32_bf16(af[mf], b1, acc[mf][1], 0, 0, 0);
    }
    __syncthreads();
  }
  #pragma unroll
  for(int nf=0; nf<2; nf++){
    int gcol = bn*64 + wc*32 + nf*16 + lr;
    if(gcol >= nout) continue;
    float bb = bias1[gcol] + (bias2 ? bias2[gcol] : 0.f);
    #pragma unroll
    for(int mf=0; mf<4; mf++){
      #pragma unroll
      for(int reg=0; reg<4; reg++){
        int grow = bm*128 + wr*64 + mf*16 + (l>>4)*4 + reg;
        float v = acc[mf][nf][reg] + bb;
        if(RELU) v = v>0.f ? v : 0.f;
        if(OUTBF16) ((unsigned short*)Cout)[(size_t)grow*Nld + gcol] = f2bf(v);
        else        ((float*)Cout)[(size_t)grow*Nld + gcol] = v;
      }
    }
  }
}

// ================= LSTM scan v3: 8 blocks x 4 batch ========================
__global__ __launch_bounds__(512) void lstm_v3_k(
    const float* __restrict__ gx,
    const float* __restrict__ done,
    const float* __restrict__ h0, const float* __restrict__ c0,
    const unsigned short* __restrict__ whhc,
    float* __restrict__ hs, float* __restrict__ out_hT, float* __restrict__ out_cT){
  __shared__ float mask_lds[TT*4];
  __shared__ unsigned short hA[2][4][136];
  __shared__ __align__(16) float gxS[3][4][520];
  __shared__ __align__(16) float gW[8][256];
  int tid = threadIdx.x;
  int B0 = blockIdx.x * 4;
  int w = tid >> 6, l = tid & 63;
  int lr = l & 15, lg = l >> 4;
  int cu = 16*w + (l >> 2);
  int cb = l & 3;
  int drow = w >> 1, dhalf = w & 1;

  bf16x8 wA[4][4];
  #pragma unroll
  for(int g=0; g<4; g++)
    #pragma unroll
    for(int kt=0; kt<4; kt++)
      wA[g][kt] = *(const bf16x8*)&whhc[(size_t)(g*128 + 16*w + lr)*128 + kt*32 + lg*8];

  {
    int tt = tid >> 2, bb = tid & 3;
    mask_lds[tid] = 1.f - done[tt*32 + B0 + bb];
  }
  float cv = c0[(size_t)(B0+cb)*128 + cu];
  float hv0 = h0[(size_t)(B0+cb)*128 + cu];
  float hout = 0.f;
  {
    float m0 = 1.f - done[0*BB + B0 + cb];
    hA[0][cb][cu] = f2bf(hv0 * m0);
  }
  #pragma unroll
  for(int sl=0; sl<2; sl++)
    gload_lds16(gx + ((size_t)(sl*32 + B0 + drow))*512 + dhalf*256 + l*4,
                &gxS[sl][drow][dhalf*256]);
  __syncthreads();

  int slot = 0;
  for(int t=0; t<TT; t++){
    int cur = t & 1;
    {
      int ts = (t+2 < TT) ? t+2 : TT-1;
      int s2 = (slot >= 1) ? slot-1 : 2;
      gload_lds16(gx + ((size_t)(ts*32 + B0 + drow))*512 + dhalf*256 + l*4,
                  &gxS[s2][drow][dhalf*256]);
    }
    bf16x8 hF[4];
    #pragma unroll
    for(int kt=0; kt<4; kt++)
      hF[kt] = *(const bf16x8*)&hA[cur][lr & 3][kt*32 + lg*8];
    f32x4 acc[4] = {};
    #pragma unroll
    for(int kt=0; kt<4; kt++)
      #pragma unroll
      for(int g=0; g<4; g++)
        acc[g] = __builtin_amdgcn_mfma_f32_16x16x32_bf16(wA[g][kt], hF[kt], acc[g], 0, 0, 0);
    if(lr < 4){
      #pragma unroll
      for(int g=0; g<4; g++)
        #pragma unroll
        for(int r=0; r<4; r++)
          gW[w][g*64 + (lg*4 + r)*4 + lr] = acc[g][r];
    }
    asm volatile("s_waitcnt lgkmcnt(0)" ::: "memory");
    float g0 = gW[w][      l];
    float g1 = gW[w][ 64 + l];
    float g2 = gW[w][128 + l];
    float g3 = gW[w][192 + l];
    float gx0 = gxS[slot][cb][      cu];
    float gx1 = gxS[slot][cb][128 + cu];
    float gx2 = gxS[slot][cb][256 + cu];
    float gx3 = gxS[slot][cb][384 + cu];
    float m  = mask_lds[t*4 + cb];
    float mn = (t < TT-1) ? mask_lds[(t+1)*4 + cb] : 1.f;
    float iv = fsig (g0 + gx0);
    float fv = fsig (g1 + gx1);
    float gv = ftanh(g2 + gx2);
    float ov = fsig (g3 + gx3);
    float cn = fv*(cv*m) + iv*gv;
    float hn = ov*ftanh(cn);
    cv = cn; hout = hn;
    hs[((size_t)t*BB + B0 + cb)*128 + cu] = hn;
    hA[cur^1][cb][cu] = f2bf(hn * mn);
    asm volatile("s_waitcnt vmcnt(3) lgkmcnt(0)" ::: "memory");
    __builtin_amdgcn_s_barrier();
    slot = (slot >= 2) ? 0 : slot+1;
  }
  out_hT[(size_t)(B0+cb)*128 + cu] = hout;
  out_cT[(size_t)(B0+cb)*128 + cu] = cv;
}

// ================= heads ===================================================
__global__ __launch_bounds__(256) void heads_k(const float* __restrict__ hs,
    const float* __restrict__ Wa, const float* __restrict__ ba,
    const float* __restrict__ Wc, const float* __restrict__ bc,
    float* __restrict__ out){
  int gid = blockIdx.x*256 + threadIdx.x;  // 4096*7
  int n = gid/7, a = gid - n*7;
  const float* w = (a<6) ? (Wa + a*128) : Wc;
  float bias = (a<6) ? ba[a] : bc[0];
  const float* h = hs + (size_t)n*128;
  float acc = 0.f;
  #pragma unroll
  for(int k=0;k<32;k++){
    f4 hv = *(const f4*)(h + k*4);
    f4 wv = *(const f4*)(w + k*4);
    acc += hv[0]*wv[0]+hv[1]*wv[1]+hv[2]*wv[2]+hv[3]*wv[3];
  }
  float v = acc + bias;
  if(a<6) out[(size_t)n*6 + a] = v;
  else    out[24576 + n] = v;
}

extern "C" void kernel_launch(void* const* d_in, const int* in_sizes, int n_in,
                              void* d_out, int out_size, void* d_ws, size_t ws_size,
                              hipStream_t stream){
  const float* x    = (const float*)d_in[0];
  const float* done = (const float*)d_in[1];
  const float* h0   = (const float*)d_in[2];
  const float* c0   = (const float*)d_in[3];
  const float* W1   = (const float*)d_in[4];
  const float* b1   = (const float*)d_in[5];
  const float* W2   = (const float*)d_in[6];
  const float* b2   = (const float*)d_in[7];
  const float* W3   = (const float*)d_in[8];
  const float* b3   = (const float*)d_in[9];
  const float* Wfc  = (const float*)d_in[10];
  const float* bfc  = (const float*)d_in[11];
  const float* W_ih = (const float*)d_in[12];
  const float* W_hh = (const float*)d_in[13];
  const float* b_ih = (const float*)d_in[14];
  const float* b_hh = (const float*)d_in[15];
  const float* Wa   = (const float*)d_in[16];
  const float* ba   = (const float*)d_in[17];
  const float* Wc   = (const float*)d_in[18];
  const float* bc   = (const float*)d_in[19];
  float* out = (float*)d_out;

  char* ws = (char*)d_ws;
  // region plan (bytes):
  //  z2   [0, 42467328)            (n,81,64) bf16   [conv12 -> conv3]
  //  z3   [42467328, 68157440)     (n,49,64) bf16   [conv3 -> FC]
  //  hid  [68157440, 72351744)     (4096,512) bf16
  //  gx   [72351744, 80740352)     (4096,512) f32
  //  hs   [80740352, 82837504)     (4096,128) f32
  //  w1c  [82837504, +8192) w2c +64K w3c +72K wfcc +3136K wihc +512K whhc +128K
  unsigned short* z2   = (unsigned short*)(ws + 0);
  unsigned short* z3   = (unsigned short*)(ws + 42467328);
  unsigned short* hid  = (unsigned short*)(ws + 68157440);
  float* gx            = (float*)(ws + 72351744);
  float* hs            = (float*)(ws + 80740352);
  unsigned short* w1c  = (unsigned short*)(ws + 82837504);
  unsigned short* w2c  = (unsigned short*)(ws + 82845696);
  unsigned short* w3c  = (unsigned short*)(ws + 82911232);
  unsigned short* wfcc = (unsigned short*)(ws + 82984960);
  unsigned short* wihc = (unsigned short*)(ws + 86196224);
  unsigned short* whhc = (unsigned short*)(ws + 86720512);

  prep_all<<<7832,256,0,stream>>>(W1, W2, W3, Wfc, W_ih, W_hh,
                                  w1c, w2c, w3c, wfcc, wihc, whhc);

  // fused conv1+conv2: 1 block per image, 512 threads, no LDS staging
  conv12_k<<<4096,512,0,stream>>>(x, w1c, b1, w2c, b2, z2);
  // conv3: M=4096*49, N=64, K=576 (XCD-swizzled: 1568 % 8 == 0)
  mgemm_k<2,1,1,1><<<dim3(1,1568),256,0,stream>>>(z2, w3c, b3, nullptr, z3, 576, 64, 64);
  // FC: M=4096, N=512, K=3136 -> hid bf16 relu
  mgemm_k<0,1,1,0><<<dim3(8,32),256,0,stream>>>(z3, wfcc, bfc, nullptr, hid, 3136, 512, 512);
  // gates: M=4096, N=512, K=512 -> gx f32
  mgemm_k<0,0,0,0><<<dim3(8,32),256,0,stream>>>(hid, wihc, b_ih, b_hh, gx, 512, 512, 512);

  lstm_v3_k<<<8,512,0,stream>>>(gx, done, h0, c0, whhc, hs, out+28672, out+32768);
  heads_k<<<112,256,0,stream>>>(hs, Wa, ba, Wc, bc, out);
}

// Round 13
// 314.687 us; speedup vs baseline: 1.0387x; 1.0387x over previous
//
#include <hip/hip_runtime.h>

#define TT 128
#define BB 32
#define NN (TT*BB)   // 4096

typedef float f4 __attribute__((ext_vector_type(4)));
typedef float f32x4 __attribute__((ext_vector_type(4)));
typedef short s8 __attribute__((ext_vector_type(8)));
typedef short bf16x8 __attribute__((ext_vector_type(8)));
typedef short s4v __attribute__((ext_vector_type(4)));

__device__ __forceinline__ float bf2f(unsigned short u){
  union{unsigned int i; float f;} x; x.i = ((unsigned int)u)<<16; return x.f;
}
__device__ __forceinline__ unsigned short f2bf(float f){
  union{float ff; unsigned int i;} x; x.ff=f;
  unsigned int r = x.i + 0x7FFFu + ((x.i>>16)&1u);
  return (unsigned short)(r>>16);
}
__device__ __forceinline__ float fsig(float x){
  return __builtin_amdgcn_rcpf(1.f + __expf(-x));
}
__device__ __forceinline__ float ftanh(float x){
  return 1.f - 2.f*__builtin_amdgcn_rcpf(1.f + __expf(2.f*x));
}
__device__ __forceinline__ void gload_lds16(const void* g, void* lds){
  __builtin_amdgcn_global_load_lds(
    (const __attribute__((address_space(1))) unsigned int*)g,
    (__attribute__((address_space(3))) unsigned int*)lds, 16, 0, 0);
}
// load 8 f32 from global, convert to bf16x8 in-register
__device__ __forceinline__ bf16x8 ldcvt8(const float* p){
  f4 u0 = *(const f4*)p;
  f4 u1 = *(const f4*)(p + 4);
  bf16x8 r;
  #pragma unroll
  for(int j=0;j<4;j++){ r[j] = (short)f2bf(u0[j]); r[4+j] = (short)f2bf(u1[j]); }
  return r;
}

// ================= merged weight prep (1 launch) ===========================
__global__ __launch_bounds__(256) void prep_all(
    const float* __restrict__ W1, const float* __restrict__ W2,
    const float* __restrict__ W3, const float* __restrict__ Wfc,
    const float* __restrict__ W_ih, const float* __restrict__ W_hh,
    unsigned short* __restrict__ w1c, unsigned short* __restrict__ w2c,
    unsigned short* __restrict__ w3c, unsigned short* __restrict__ wfcc,
    unsigned short* __restrict__ wihc, unsigned short* __restrict__ whhc){
  int i = blockIdx.x*256 + threadIdx.x;
  if(i < 1605632){
    int nn = i/3136; int rem = i - nn*3136; int sp = rem >> 6; int ci = rem & 63;
    wfcc[i] = f2bf(Wfc[nn*3136 + ci*49 + sp]); return;
  }
  i -= 1605632;
  if(i < 262144){ wihc[i] = f2bf(W_ih[i]); return; }
  i -= 262144;
  if(i < 65536){ whhc[i] = f2bf(W_hh[i]); return; }
  i -= 65536;
  if(i < 36864){
    int co = i/576; int rem = i - co*576; int khw = rem >> 6; int ci = rem & 63;
    w3c[i] = f2bf(W3[(co*64 + ci)*9 + khw]); return;
  }
  i -= 36864;
  if(i < 32768){
    int co = i >> 9; int rem = i & 511; int khw = rem >> 5; int ci = rem & 31;
    w2c[i] = f2bf(W2[(co*32 + ci)*16 + khw]); return;
  }
  i -= 32768;
  if(i < 2048){ w1c[i] = f2bf(W1[i] * (1.f/255.f)); }
}

// ================= fused conv1+conv2 v4: register-rich ======================
// 4096 blocks x 256 thr (4 waves), __launch_bounds__(256,2) -> VGPR-rich ILP.
// LDS = z1s only (25.6 KB). Wave w owns conv2 ch-group w; ALL 16 w2 frags
// hoisted into 64 VGPRs BEFORE conv1 (L2 latency hides under conv1 compute).
// conv1: direct-global x reads + in-reg cvt (R12-proven); z1s XOR-swizzled.
// conv2: pure ds_read+MFMA, 6 independent acc chains.
__global__ __launch_bounds__(256, 2) void conv12_k(
    const float* __restrict__ x,
    const unsigned short* __restrict__ w1c, const float* __restrict__ b1,
    const unsigned short* __restrict__ w2c, const float* __restrict__ b2,
    unsigned short* __restrict__ z2){
  __shared__ unsigned short z1s[200*64];    // 25600 B (swizzled)
  int t = threadIdx.x;
  int n = blockIdx.x;
  int w = t >> 6, l = t & 63;
  int lr = l & 15, lg = l >> 4;

  // ---- hoist conv2 weights for ch-group w (16 bf16x8 = 64 VGPR), issued now
  const unsigned short* wrow = w2c + (size_t)(w*16+lr)*512 + lg*8;
  bf16x8 w2r[16];
  #pragma unroll
  for(int s=0;s<16;s++) w2r[s] = *(const bf16x8*)(wrow + s*32);

  // ---- conv1: D[ch][pixel] = mfma(w1_frag, x_frag), tiles mt = w,w+4,... ----
  {
    bf16x8 wf1[2][2];   // [nt][s] from global (L2-broadcast)
    #pragma unroll
    for(int nt=0;nt<2;nt++)
      #pragma unroll
      for(int s=0;s<2;s++)
        wf1[nt][s] = *(const bf16x8*)&w1c[(nt*16+lr)*64 + s*32 + lg*8];
    f4 b1v[2];
    b1v[0] = *(const f4*)&b1[lg*4];
    b1v[1] = *(const f4*)&b1[16 + lg*4];
    const float* xb = x + (size_t)n*7056;
    for(int mt=w; mt<25; mt+=4){
      int p = mt*16 + lr;
      int oh = p/20, ow = p - oh*20;
      const float* xr = xb + (size_t)(oh*4 + lg)*84 + ow*4;
      bf16x8 a0 = ldcvt8(xr);           // rows oh*4+lg,   k = lg*8 + kw
      bf16x8 a1 = ldcvt8(xr + 4*84);    // rows oh*4+4+lg, k = 32 + lg*8 + kw
      f32x4 acc[2] = {};
      acc[0] = __builtin_amdgcn_mfma_f32_16x16x32_bf16(wf1[0][0], a0, acc[0], 0,0,0);
      acc[0] = __builtin_amdgcn_mfma_f32_16x16x32_bf16(wf1[0][1], a1, acc[0], 0,0,0);
      acc[1] = __builtin_amdgcn_mfma_f32_16x16x32_bf16(wf1[1][0], a0, acc[1], 0,0,0);
      acc[1] = __builtin_amdgcn_mfma_f32_16x16x32_bf16(wf1[1][1], a1, acc[1], 0,0,0);
      int row = p >> 1, par = (p & 1) << 6, swz = (row & 7) << 4;
      #pragma unroll
      for(int nt=0;nt<2;nt++){
        s4v hp;
        #pragma unroll
        for(int reg=0;reg<4;reg++){
          float v = acc[nt][reg] + b1v[nt][reg];
          v = v>0.f ? v : 0.f;
          hp[reg] = (short)f2bf(v);
        }
        int bo = (par + (nt*16 + lg*4)*2) ^ swz;
        *(s4v*)((char*)z1s + row*128 + bo) = hp;
      }
    }
  }
  __syncthreads();

  // ---- conv2: wave w = ch-group w, all 6 pixel tiles, weights in regs ----
  {
    int rb2[6];
    #pragma unroll
    for(int m=0;m<6;m++){
      int q = m*16 + lr; if(q > 80) q = 80;
      int oh = q/9, ow = q - oh*9;
      rb2[m] = 2*oh*20 + 2*ow;
    }
    f32x4 acc2[6] = {};
    #pragma unroll
    for(int s=0;s<16;s++){
      int kh = s>>2, kw = s&3;
      #pragma unroll
      for(int m=0;m<6;m++){
        int p = rb2[m] + kh*20 + kw;
        int row = p >> 1;
        int bo = (((p&1)<<6) + (lg<<4)) ^ ((row&7)<<4);
        bf16x8 bf = *(const bf16x8*)((const char*)z1s + row*128 + bo);
        acc2[m] = __builtin_amdgcn_mfma_f32_16x16x32_bf16(w2r[s], bf, acc2[m], 0,0,0);
      }
    }
    f4 b2v = *(const f4*)&b2[w*16 + lg*4];
    #pragma unroll
    for(int m=0;m<6;m++){
      int q = m*16 + lr;
      if(q < 81){
        s4v hp;
        #pragma unroll
        for(int reg=0;reg<4;reg++){
          float v = acc2[m][reg] + b2v[reg];
          v = v>0.f ? v : 0.f;
          hp[reg] = (short)f2bf(v);
        }
        *(s4v*)&z2[((size_t)n*81 + q)*64 + w*16 + lg*4] = hp;
      }
    }
  }
}

// ================= unified MFMA GEMM =======================================
// MODE 0: plain A rows. MODE 2: conv3 implicit (z2 NHWC 9x9x64).
// SWZ: XCD-chunked bm remap (needs gridDim.y % 8 == 0).
template<int MODE, int OUTBF16, int RELU, int SWZ>
__global__ __launch_bounds__(256) void mgemm_k(
    const unsigned short* __restrict__ A, const unsigned short* __restrict__ B,
    const float* __restrict__ bias1, const float* __restrict__ bias2,
    void* __restrict__ Cout, int K, int Nld, int nout){
  __shared__ unsigned short As[128*40];
  __shared__ unsigned short Bs[64*40];
  int t = threadIdx.x;
  int bm = blockIdx.y, bn = blockIdx.x;
  if(SWZ){
    int cpx = gridDim.y >> 3;
    bm = (bm & 7)*cpx + (bm >> 3);
  }
  int arow = t >> 1, ahalf = t & 1;
  int gm = bm*128 + arow;
  const unsigned short* abase;
  if(MODE == 0){
    abase = A + (size_t)gm*K + ahalf*16;
  } else {
    int n = gm/49; int r = gm - n*49; int oh = r/7; int ow = r - oh*7;
    abase = A + (((size_t)n*9 + oh)*9 + ow)*64 + ahalf*16;
  }
  int brow = t >> 2, bq = t & 3;
  const unsigned short* bbase = B + (size_t)(bn*64 + brow)*K + bq*8;
  int l = t & 63, w = t >> 6;
  int wr = w >> 1, wc = w & 1;
  int lr = l & 15, lk = (l >> 4)*8;
  f32x4 acc[4][2] = {};
  int nsteps = K >> 5;
  for(int s=0; s<nsteps; s++){
    const unsigned short* src;
    if(MODE == 0){
      src = abase + s*32;
    } else {
      int khw = s >> 1; int kh = khw/3; int kw = khw - kh*3;
      src = abase + (kh*9 + kw)*64 + (s & 1)*32;
    }
    bf16x8 a0 = *(const bf16x8*)src;
    bf16x8 a1 = *(const bf16x8*)(src + 8);
    *(bf16x8*)&As[arow*40 + ahalf*16] = a0;
    *(bf16x8*)&As[arow*40 + ahalf*16 + 8] = a1;
    bf16x8 bv = *(const bf16x8*)(bbase + s*32);
    *(bf16x8*)&Bs[brow*40 + bq*8] = bv;
    __syncthreads();
    bf16x8 af[4];
    #pragma unroll
    for(int mf=0; mf<4; mf++)
      af[mf] = *(const bf16x8*)&As[(wr*64 + mf*16 + lr)*40 + lk];
    bf16x8 b0 = *(const bf16x8*)&Bs[(wc*32 + lr)*40 + lk];
    bf16x8 b1 = *(const bf16x8*)&Bs[(wc*32 + 16 + lr)*40 + lk];
    #pragma unroll
    for(int mf=0; mf<4; mf++){
      acc[mf][0] = __builtin_amdgcn_mfma_f32_16x16x32_bf16(af[mf], b0, acc[mf][0], 0, 0, 0);
      acc[mf][1] = __builtin_amdgcn_mfma_f32_16x16x32_bf16(af[mf], b1, acc[mf][1], 0, 0, 0);
    }
    __syncthreads();
  }
  #pragma unroll
  for(int nf=0; nf<2; nf++){
    int gcol = bn*64 + wc*32 + nf*16 + lr;
    if(gcol >= nout) continue;
    float bb = bias1[gcol] + (bias2 ? bias2[gcol] : 0.f);
    #pragma unroll
    for(int mf=0; mf<4; mf++){
      #pragma unroll
      for(int reg=0; reg<4; reg++){
        int grow = bm*128 + wr*64 + mf*16 + (l>>4)*4 + reg;
        float v = acc[mf][nf][reg] + bb;
        if(RELU) v = v>0.f ? v : 0.f;
        if(OUTBF16) ((unsigned short*)Cout)[(size_t)grow*Nld + gcol] = f2bf(v);
        else        ((float*)Cout)[(size_t)grow*Nld + gcol] = v;
      }
    }
  }
}

// ================= LSTM scan v3: 8 blocks x 4 batch ========================
__global__ __launch_bounds__(512) void lstm_v3_k(
    const float* __restrict__ gx,
    const float* __restrict__ done,
    const float* __restrict__ h0, const float* __restrict__ c0,
    const unsigned short* __restrict__ whhc,
    float* __restrict__ hs, float* __restrict__ out_hT, float* __restrict__ out_cT){
  __shared__ float mask_lds[TT*4];
  __shared__ unsigned short hA[2][4][136];
  __shared__ __align__(16) float gxS[3][4][520];
  __shared__ __align__(16) float gW[8][256];
  int tid = threadIdx.x;
  int B0 = blockIdx.x * 4;
  int w = tid >> 6, l = tid & 63;
  int lr = l & 15, lg = l >> 4;
  int cu = 16*w + (l >> 2);
  int cb = l & 3;
  int drow = w >> 1, dhalf = w & 1;

  bf16x8 wA[4][4];
  #pragma unroll
  for(int g=0; g<4; g++)
    #pragma unroll
    for(int kt=0; kt<4; kt++)
      wA[g][kt] = *(const bf16x8*)&whhc[(size_t)(g*128 + 16*w + lr)*128 + kt*32 + lg*8];

  {
    int tt = tid >> 2, bb = tid & 3;
    mask_lds[tid] = 1.f - done[tt*32 + B0 + bb];
  }
  float cv = c0[(size_t)(B0+cb)*128 + cu];
  float hv0 = h0[(size_t)(B0+cb)*128 + cu];
  float hout = 0.f;
  {
    float m0 = 1.f - done[0*BB + B0 + cb];
    hA[0][cb][cu] = f2bf(hv0 * m0);
  }
  #pragma unroll
  for(int sl=0; sl<2; sl++)
    gload_lds16(gx + ((size_t)(sl*32 + B0 + drow))*512 + dhalf*256 + l*4,
                &gxS[sl][drow][dhalf*256]);
  __syncthreads();

  int slot = 0;
  for(int t=0; t<TT; t++){
    int cur = t & 1;
    {
      int ts = (t+2 < TT) ? t+2 : TT-1;
      int s2 = (slot >= 1) ? slot-1 : 2;
      gload_lds16(gx + ((size_t)(ts*32 + B0 + drow))*512 + dhalf*256 + l*4,
                  &gxS[s2][drow][dhalf*256]);
    }
    bf16x8 hF[4];
    #pragma unroll
    for(int kt=0; kt<4; kt++)
      hF[kt] = *(const bf16x8*)&hA[cur][lr & 3][kt*32 + lg*8];
    f32x4 acc[4] = {};
    #pragma unroll
    for(int kt=0; kt<4; kt++)
      #pragma unroll
      for(int g=0; g<4; g++)
        acc[g] = __builtin_amdgcn_mfma_f32_16x16x32_bf16(wA[g][kt], hF[kt], acc[g], 0, 0, 0);
    if(lr < 4){
      #pragma unroll
      for(int g=0; g<4; g++)
        #pragma unroll
        for(int r=0; r<4; r++)
          gW[w][g*64 + (lg*4 + r)*4 + lr] = acc[g][r];
    }
    asm volatile("s_waitcnt lgkmcnt(0)" ::: "memory");
    float g0 = gW[w][      l];
    float g1 = gW[w][ 64 + l];
    float g2 = gW[w][128 + l];
    float g3 = gW[w][192 + l];
    float gx0 = gxS[slot][cb][      cu];
    float gx1 = gxS[slot][cb][128 + cu];
    float gx2 = gxS[slot][cb][256 + cu];
    float gx3 = gxS[slot][cb][384 + cu];
    float m  = mask_lds[t*4 + cb];
    float mn = (t < TT-1) ? mask_lds[(t+1)*4 + cb] : 1.f;
    float iv = fsig (g0 + gx0);
    float fv = fsig (g1 + gx1);
    float gv = ftanh(g2 + gx2);
    float ov = fsig (g3 + gx3);
    float cn = fv*(cv*m) + iv*gv;
    float hn = ov*ftanh(cn);
    cv = cn; hout = hn;
    hs[((size_t)t*BB + B0 + cb)*128 + cu] = hn;
    hA[cur^1][cb][cu] = f2bf(hn * mn);
    asm volatile("s_waitcnt vmcnt(3) lgkmcnt(0)" ::: "memory");
    __builtin_amdgcn_s_barrier();
    slot = (slot >= 2) ? 0 : slot+1;
  }
  out_hT[(size_t)(B0+cb)*128 + cu] = hout;
  out_cT[(size_t)(B0+cb)*128 + cu] = cv;
}

// ================= heads ===================================================
__global__ __launch_bounds__(256) void heads_k(const float* __restrict__ hs,
    const float* __restrict__ Wa, const float* __restrict__ ba,
    const float* __restrict__ Wc, const float* __restrict__ bc,
    float* __restrict__ out){
  int gid = blockIdx.x*256 + threadIdx.x;  // 4096*7
  int n = gid/7, a = gid - n*7;
  const float* w = (a<6) ? (Wa + a*128) : Wc;
  float bias = (a<6) ? ba[a] : bc[0];
  const float* h = hs + (size_t)n*128;
  float acc = 0.f;
  #pragma unroll
  for(int k=0;k<32;k++){
    f4 hv = *(const f4*)(h + k*4);
    f4 wv = *(const f4*)(w + k*4);
    acc += hv[0]*wv[0]+hv[1]*wv[1]+hv[2]*wv[2]+hv[3]*wv[3];
  }
  float v = acc + bias;
  if(a<6) out[(size_t)n*6 + a] = v;
  else    out[24576 + n] = v;
}

extern "C" void kernel_launch(void* const* d_in, const int* in_sizes, int n_in,
                              void* d_out, int out_size, void* d_ws, size_t ws_size,
                              hipStream_t stream){
  const float* x    = (const float*)d_in[0];
  const float* done = (const float*)d_in[1];
  const float* h0   = (const float*)d_in[2];
  const float* c0   = (const float*)d_in[3];
  const float* W1   = (const float*)d_in[4];
  const float* b1   = (const float*)d_in[5];
  const float* W2   = (const float*)d_in[6];
  const float* b2   = (const float*)d_in[7];
  const float* W3   = (const float*)d_in[8];
  const float* b3   = (const float*)d_in[9];
  const float* Wfc  = (const float*)d_in[10];
  const float* bfc  = (const float*)d_in[11];
  const float* W_ih = (const float*)d_in[12];
  const float* W_hh = (const float*)d_in[13];
  const float* b_ih = (const float*)d_in[14];
  const float* b_hh = (const float*)d_in[15];
  const float* Wa   = (const float*)d_in[16];
  const float* ba   = (const float*)d_in[17];
  const float* Wc   = (const float*)d_in[18];
  const float* bc   = (const float*)d_in[19];
  float* out = (float*)d_out;

  char* ws = (char*)d_ws;
  // region plan (bytes):
  //  z2   [0, 42467328)            (n,81,64) bf16   [conv12 -> conv3]
  //  z3   [42467328, 68157440)     (n,49,64) bf16   [conv3 -> FC]
  //  hid  [68157440, 72351744)     (4096,512) bf16
  //  gx   [72351744, 80740352)     (4096,512) f32
  //  hs   [80740352, 82837504)     (4096,128) f32
  //  w1c  [82837504, +8192) w2c +64K w3c +72K wfcc +3136K wihc +512K whhc +128K
  unsigned short* z2   = (unsigned short*)(ws + 0);
  unsigned short* z3   = (unsigned short*)(ws + 42467328);
  unsigned short* hid  = (unsigned short*)(ws + 68157440);
  float* gx            = (float*)(ws + 72351744);
  float* hs            = (float*)(ws + 80740352);
  unsigned short* w1c  = (unsigned short*)(ws + 82837504);
  unsigned short* w2c  = (unsigned short*)(ws + 82845696);
  unsigned short* w3c  = (unsigned short*)(ws + 82911232);
  unsigned short* wfcc = (unsigned short*)(ws + 82984960);
  unsigned short* wihc = (unsigned short*)(ws + 86196224);
  unsigned short* whhc = (unsigned short*)(ws + 86720512);

  prep_all<<<7832,256,0,stream>>>(W1, W2, W3, Wfc, W_ih, W_hh,
                                  w1c, w2c, w3c, wfcc, wihc, whhc);

  // fused conv1+conv2 v4: 1 block per image, 256 threads, register-rich
  conv12_k<<<4096,256,0,stream>>>(x, w1c, b1, w2c, b2, z2);
  // conv3: M=4096*49, N=64, K=576 (XCD-swizzled: 1568 % 8 == 0)
  mgemm_k<2,1,1,1><<<dim3(1,1568),256,0,stream>>>(z2, w3c, b3, nullptr, z3, 576, 64, 64);
  // FC: M=4096, N=512, K=3136 -> hid bf16 relu
  mgemm_k<0,1,1,0><<<dim3(8,32),256,0,stream>>>(z3, wfcc, bfc, nullptr, hid, 3136, 512, 512);
  // gates: M=4096, N=512, K=512 -> gx f32
  mgemm_k<0,0,0,0><<<dim3(8,32),256,0,stream>>>(hid, wihc, b_ih, b_hh, gx, 512, 512, 512);

  lstm_v3_k<<<8,512,0,stream>>>(gx, done, h0, c0, whhc, hs, out+28672, out+32768);
  heads_k<<<112,256,0,stream>>>(hs, Wa, ba, Wc, bc, out);
}